// Round 3
// baseline (660.876 us; speedup 1.0000x reference)
//
#include <hip/hip_runtime.h>
#include <cstdint>

// out = sigmoid(X @ W + b)
// X: (8192 x 4096) fp32 (detected), W: (4096 x 4096) fp32 K x N, b: (4096).
// Pipeline: prep (X->bf16, W->WT bf16 transposed) then bf16 MFMA GEMM with
// BK=64 K-stages (2 compute halves per barrier pair) + fused bias+sigmoid.
#define MDIM 8192
#define NDIM 4096
#define KDIM 4096

typedef __bf16 bf16x8 __attribute__((ext_vector_type(8)));
typedef float f32x4 __attribute__((ext_vector_type(4)));

__device__ __forceinline__ void gload_lds16(const void* g, void* l) {
    // async global->LDS, 16B/lane; LDS dest = wave-uniform base + lane*16
    __builtin_amdgcn_global_load_lds(
        (const __attribute__((address_space(1))) uint32_t*)g,
        (__attribute__((address_space(3))) uint32_t*)l, 16, 0, 0);
}

__device__ __forceinline__ unsigned short bf16_bits(float f) {
    __bf16 b = (__bf16)f;
    return __builtin_bit_cast(unsigned short, b);
}

// Called by ALL threads (uses __syncthreads_and). 1 if fp32, 0 if bf16.
// X is uniform[0,1); fp32 low half-words are ~random 16-bit patterns and
// fail the "bf16 in [0,1]" test with P ~= 1 - 0.25^64.
__device__ __forceinline__ int detect_f32(const void* X) {
    int ok = 1;
    if (threadIdx.x < 128) {
        unsigned short h = ((const unsigned short*)X)[threadIdx.x];
        ok = (h <= 0x3F80);
    }
    return __syncthreads_and(ok) ? 0 : 1;
}

// ---------------- prep: X fp32->bf16 AND W (KxN) -> WT (NxK) bf16 ----------
// grid = 8192 (cvt, fp32 mode only) + 4096 (transpose) blocks
__global__ __launch_bounds__(256) void prep(const void* __restrict__ X,
                                            const void* __restrict__ W,
                                            __bf16* __restrict__ Xb,
                                            __bf16* __restrict__ WT) {
    const int f32 = detect_f32(X);
    const int t = threadIdx.x;
    if (blockIdx.x < 8192) {
        if (!f32) return;  // bf16 mode: GEMM reads X directly
        const float* Xf = (const float*)X;
        const long base = ((long)blockIdx.x * 256 + t) * 16;
#pragma unroll
        for (int c = 0; c < 2; ++c) {
            float4 v0 = *(const float4*)(Xf + base + c * 8);
            float4 v1 = *(const float4*)(Xf + base + c * 8 + 4);
            unsigned short r[8] = {bf16_bits(v0.x), bf16_bits(v0.y),
                                   bf16_bits(v0.z), bf16_bits(v0.w),
                                   bf16_bits(v1.x), bf16_bits(v1.y),
                                   bf16_bits(v1.z), bf16_bits(v1.w)};
            *(uint4*)(Xb + base + c * 8) = *(const uint4*)r;
        }
        return;
    }
    // ---- transpose part ----
    __shared__ unsigned short tile[64 * 65];
    const int bid = blockIdx.x - 8192;
    const int n0 = (bid & 63) * 64;
    const int k0 = (bid >> 6) * 64;
    if (f32) {
        const float* Wf = (const float*)W;
#pragma unroll
        for (int p = 0; p < 4; ++p) {
            const int ch = p * 256 + t;
            const int kr = ch >> 4;
            const int nc = ch & 15;
            float4 v = *(const float4*)(Wf + (long)(k0 + kr) * NDIM + n0 + nc * 4);
            tile[(nc * 4 + 0) * 65 + kr] = bf16_bits(v.x);
            tile[(nc * 4 + 1) * 65 + kr] = bf16_bits(v.y);
            tile[(nc * 4 + 2) * 65 + kr] = bf16_bits(v.z);
            tile[(nc * 4 + 3) * 65 + kr] = bf16_bits(v.w);
        }
    } else {
        const __bf16* Wb = (const __bf16*)W;
#pragma unroll
        for (int p = 0; p < 2; ++p) {
            const int ch = p * 256 + t;
            const int kr = ch >> 3;
            const int nc = ch & 7;
            uint4 v = *(const uint4*)(Wb + (long)(k0 + kr) * NDIM + n0 + nc * 8);
            const unsigned short* e = (const unsigned short*)&v;
#pragma unroll
            for (int i = 0; i < 8; ++i) tile[(nc * 8 + i) * 65 + kr] = e[i];
        }
    }
    __syncthreads();
#pragma unroll
    for (int p = 0; p < 2; ++p) {
        const int ch = p * 256 + t;
        const int nr = ch >> 3;
        const int kc = ch & 7;
        unsigned short r[8];
#pragma unroll
        for (int i = 0; i < 8; ++i) r[i] = tile[nr * 65 + kc * 8 + i];
        *(uint4*)(WT + (long)(n0 + nr) * KDIM + k0 + kc * 8) = *(uint4*)r;
    }
}

// stand-alone transpose for MODE 1 (no Xb workspace)
__global__ __launch_bounds__(256) void transpose_w(const void* __restrict__ X,
                                                   const void* __restrict__ W,
                                                   __bf16* __restrict__ WT) {
    __shared__ unsigned short tile[64 * 65];
    const int f32 = detect_f32(X);
    const int t = threadIdx.x;
    const int k0 = blockIdx.y * 64;
    const int n0 = blockIdx.x * 64;
    if (f32) {
        const float* Wf = (const float*)W;
#pragma unroll
        for (int p = 0; p < 4; ++p) {
            const int ch = p * 256 + t;
            const int kr = ch >> 4;
            const int nc = ch & 15;
            float4 v = *(const float4*)(Wf + (long)(k0 + kr) * NDIM + n0 + nc * 4);
            tile[(nc * 4 + 0) * 65 + kr] = bf16_bits(v.x);
            tile[(nc * 4 + 1) * 65 + kr] = bf16_bits(v.y);
            tile[(nc * 4 + 2) * 65 + kr] = bf16_bits(v.z);
            tile[(nc * 4 + 3) * 65 + kr] = bf16_bits(v.w);
        }
    } else {
        const __bf16* Wb = (const __bf16*)W;
#pragma unroll
        for (int p = 0; p < 2; ++p) {
            const int ch = p * 256 + t;
            const int kr = ch >> 3;
            const int nc = ch & 7;
            uint4 v = *(const uint4*)(Wb + (long)(k0 + kr) * NDIM + n0 + nc * 8);
            const unsigned short* e = (const unsigned short*)&v;
#pragma unroll
            for (int i = 0; i < 8; ++i) tile[(nc * 8 + i) * 65 + kr] = e[i];
        }
    }
    __syncthreads();
#pragma unroll
    for (int p = 0; p < 2; ++p) {
        const int ch = p * 256 + t;
        const int nr = ch >> 3;
        const int kc = ch & 7;
        unsigned short r[8];
#pragma unroll
        for (int i = 0; i < 8; ++i) r[i] = tile[nr * 65 + kc * 8 + i];
        *(uint4*)(WT + (long)(n0 + nr) * KDIM + k0 + kc * 8) = *(uint4*)r;
    }
}

// ---------------- fused GEMM + bias + sigmoid ----------------
// MODE 0: A from Xb(fp32)/X(bf16), B from WT, both glds; BK=64, 2 halves/stage
// MODE 1: no Xb; fp32 A converted during LDS staging; B from WT (BK=32)
// MODE 2: no workspace; A as MODE1, B transposed/converted in-kernel (BK=32)
template <int MODE>
__global__ __launch_bounds__(256) void gemm_bias_sigmoid(
    const void* __restrict__ X, const __bf16* __restrict__ Xb,
    const void* __restrict__ Wp, const __bf16* __restrict__ WT,
    const void* __restrict__ bias, void* __restrict__ out) {
    __shared__ __bf16 sA[128 * 64];  // MODE0: [m][64] k-contig; MODE1/2: [m][32]
    __shared__ __bf16 sB[128 * 64];
    const int f32 = detect_f32(X);
    const int t = threadIdx.x;
    const int lane = t & 63;
    const int wid = t >> 6;
    const int m0 = blockIdx.y * 128;
    const int n0 = blockIdx.x * 128;
    const int wm = (wid & 1) * 64;
    const int wn = (wid >> 1) * 64;
    const int lrow = lane & 15;
    const int quad = lane >> 4;

    f32x4 acc[4][4] = {};

    if constexpr (MODE == 0) {
        // ---- BK=64 main path ----
        const __bf16* Abf = f32 ? Xb : (const __bf16*)X;
        const int r8 = lane >> 3;  // 0..7 row within 8-row slab
        const int c8 = lane & 7;   // 16B chunk within 128B row
        const __bf16* gA = Abf + (long)(m0 + wid * 32 + r8) * KDIM + c8 * 8;
        const __bf16* gB = WT + (long)(n0 + wid * 32 + r8) * KDIM + c8 * 8;
        __bf16* lA = sA + wid * 32 * 64;  // wave-uniform
        __bf16* lB = sB + wid * 32 * 64;

        for (int kt = 0; kt < KDIM / 64; ++kt) {
            const int kb = kt * 64;
#pragma unroll
            for (int i = 0; i < 4; ++i) {
                gload_lds16(gA + kb + (long)i * 8 * KDIM, lA + i * 512);
                gload_lds16(gB + kb + (long)i * 8 * KDIM, lB + i * 512);
            }
            __syncthreads();
#pragma unroll
            for (int h = 0; h < 2; ++h) {
                bf16x8 aF[4], bF[4];
                const __bf16* pa = sA + (wm + lrow) * 64 + h * 32 + quad * 8;
                const __bf16* pb = sB + (wn + lrow) * 64 + h * 32 + quad * 8;
#pragma unroll
                for (int i = 0; i < 4; ++i)
                    aF[i] = *(const bf16x8*)(pa + i * 1024);
#pragma unroll
                for (int j = 0; j < 4; ++j)
                    bF[j] = *(const bf16x8*)(pb + j * 1024);
#pragma unroll
                for (int i = 0; i < 4; ++i)
#pragma unroll
                    for (int j = 0; j < 4; ++j)
                        acc[i][j] = __builtin_amdgcn_mfma_f32_16x16x32_bf16(
                            aF[i], bF[j], acc[i][j], 0, 0, 0);
            }
            __syncthreads();
        }
    } else {
        // ---- BK=32 fallback paths (round-2 verified) ----
        const int srow = t >> 2;
        const int schk = t & 3;
        __bf16* ldsA = sA + wid * 512;
        __bf16* ldsB = sB + wid * 512;
        const int arow = t >> 1;
        const int acol = (t & 1) * 16;
        const int fp = t & 15;
        const int fc = t >> 4;
        uint32_t* sB32 = (uint32_t*)sB;

        auto compute = [&]() {
            bf16x8 aF[4], bF[4];
            const __bf16* pa = sA + (wm + lrow) * 32 + quad * 8;
            const __bf16* pb = sB + (wn + lrow) * 32 + quad * 8;
#pragma unroll
            for (int i = 0; i < 4; ++i) aF[i] = *(const bf16x8*)(pa + i * 512);
#pragma unroll
            for (int j = 0; j < 4; ++j) bF[j] = *(const bf16x8*)(pb + j * 512);
#pragma unroll
            for (int i = 0; i < 4; ++i)
#pragma unroll
                for (int j = 0; j < 4; ++j)
                    acc[i][j] = __builtin_amdgcn_mfma_f32_16x16x32_bf16(
                        aF[i], bF[j], acc[i][j], 0, 0, 0);
        };

        if (MODE == 1 && !f32) {
            const __bf16* gA = (const __bf16*)X + (long)(m0 + srow) * KDIM + schk * 8;
            const __bf16* gB = WT + (long)(n0 + srow) * KDIM + schk * 8;
            for (int kt = 0; kt < KDIM / 32; ++kt) {
                const __bf16* a0 = gA + kt * 32;
                gload_lds16(a0, ldsA);
                gload_lds16(a0 + (long)64 * KDIM, ldsA + 2048);
                const __bf16* b0 = gB + kt * 32;
                gload_lds16(b0, ldsB);
                gload_lds16(b0 + (long)64 * KDIM, ldsB + 2048);
                __syncthreads();
                compute();
                __syncthreads();
            }
        } else if (MODE == 1) {
            const float* Xf = (const float*)X;
            const __bf16* gB = WT + (long)(n0 + srow) * KDIM + schk * 8;
            for (int kt = 0; kt < KDIM / 32; ++kt) {
                const __bf16* b0 = gB + kt * 32;
                gload_lds16(b0, ldsB);
                gload_lds16(b0 + (long)64 * KDIM, ldsB + 2048);
                const float* ap = Xf + (long)(m0 + arow) * KDIM + kt * 32 + acol;
                float4 v0 = *(const float4*)(ap);
                float4 v1 = *(const float4*)(ap + 4);
                float4 v2 = *(const float4*)(ap + 8);
                float4 v3 = *(const float4*)(ap + 12);
                unsigned short r[16] = {
                    bf16_bits(v0.x), bf16_bits(v0.y), bf16_bits(v0.z), bf16_bits(v0.w),
                    bf16_bits(v1.x), bf16_bits(v1.y), bf16_bits(v1.z), bf16_bits(v1.w),
                    bf16_bits(v2.x), bf16_bits(v2.y), bf16_bits(v2.z), bf16_bits(v2.w),
                    bf16_bits(v3.x), bf16_bits(v3.y), bf16_bits(v3.z), bf16_bits(v3.w)};
                *(uint4*)(sA + arow * 32 + acol) = *(const uint4*)(r);
                *(uint4*)(sA + arow * 32 + acol + 8) = *(const uint4*)(r + 8);
                __syncthreads();
                compute();
                __syncthreads();
            }
        } else if (MODE == 2 && !f32) {
            const __bf16* gA = (const __bf16*)X + (long)(m0 + srow) * KDIM + schk * 8;
            const __bf16* Wb = (const __bf16*)Wp;
            for (int kt = 0; kt < KDIM / 32; ++kt) {
                const __bf16* a0 = gA + kt * 32;
                gload_lds16(a0, ldsA);
                gload_lds16(a0 + (long)64 * KDIM, ldsA + 2048);
                const __bf16* w0 = Wb + (long)(kt * 32 + 2 * fp) * NDIM + n0 + fc * 8;
                uint4 g0 = *(const uint4*)(w0);
                uint4 g1 = *(const uint4*)(w0 + NDIM);
                const unsigned short* e0 = (const unsigned short*)&g0;
                const unsigned short* e1 = (const unsigned short*)&g1;
#pragma unroll
                for (int i = 0; i < 8; ++i)
                    sB32[(fc * 8 + i) * 16 + fp] =
                        (uint32_t)e0[i] | ((uint32_t)e1[i] << 16);
                __syncthreads();
                compute();
                __syncthreads();
            }
        } else if (MODE == 2) {
            const float* Xf = (const float*)X;
            const float* Wf = (const float*)Wp;
            for (int kt = 0; kt < KDIM / 32; ++kt) {
                const float* ap = Xf + (long)(m0 + arow) * KDIM + kt * 32 + acol;
                float4 v0 = *(const float4*)(ap);
                float4 v1 = *(const float4*)(ap + 4);
                float4 v2 = *(const float4*)(ap + 8);
                float4 v3 = *(const float4*)(ap + 12);
                unsigned short r[16] = {
                    bf16_bits(v0.x), bf16_bits(v0.y), bf16_bits(v0.z), bf16_bits(v0.w),
                    bf16_bits(v1.x), bf16_bits(v1.y), bf16_bits(v1.z), bf16_bits(v1.w),
                    bf16_bits(v2.x), bf16_bits(v2.y), bf16_bits(v2.z), bf16_bits(v2.w),
                    bf16_bits(v3.x), bf16_bits(v3.y), bf16_bits(v3.z), bf16_bits(v3.w)};
                *(uint4*)(sA + arow * 32 + acol) = *(const uint4*)(r);
                *(uint4*)(sA + arow * 32 + acol + 8) = *(const uint4*)(r + 8);
                const float* w0 = Wf + (long)(kt * 32 + 2 * fp) * NDIM + n0 + fc * 8;
                float4 u0 = *(const float4*)(w0);
                float4 u1 = *(const float4*)(w0 + 4);
                float4 u2 = *(const float4*)(w0 + NDIM);
                float4 u3 = *(const float4*)(w0 + NDIM + 4);
                float k0v[8] = {u0.x, u0.y, u0.z, u0.w, u1.x, u1.y, u1.z, u1.w};
                float k1v[8] = {u2.x, u2.y, u2.z, u2.w, u3.x, u3.y, u3.z, u3.w};
#pragma unroll
                for (int i = 0; i < 8; ++i)
                    sB32[(fc * 8 + i) * 16 + fp] =
                        (uint32_t)bf16_bits(k0v[i]) |
                        ((uint32_t)bf16_bits(k1v[i]) << 16);
                __syncthreads();
                compute();
                __syncthreads();
            }
        }
    }

    // epilogue: C/D layout col=lane&15, row=quad*4+reg
    const int crow = m0 + wm + quad * 4;
    if (f32) {
        float* of = (float*)out;
        const float* bf = (const float*)bias;
#pragma unroll
        for (int j = 0; j < 4; ++j) {
            const int col = n0 + wn + j * 16 + lrow;
            const float bv = bf[col];
#pragma unroll
            for (int i = 0; i < 4; ++i) {
                const long rbase = (long)(crow + i * 16) * NDIM + col;
#pragma unroll
                for (int r = 0; r < 4; ++r) {
                    const float x = acc[i][j][r] + bv;
                    of[rbase + (long)r * NDIM] = 1.0f / (1.0f + __expf(-x));
                }
            }
        }
    } else {
        __bf16* ob = (__bf16*)out;
        const __bf16* bb = (const __bf16*)bias;
#pragma unroll
        for (int j = 0; j < 4; ++j) {
            const int col = n0 + wn + j * 16 + lrow;
            const float bv = (float)bb[col];
#pragma unroll
            for (int i = 0; i < 4; ++i) {
                const long rbase = (long)(crow + i * 16) * NDIM + col;
#pragma unroll
                for (int r = 0; r < 4; ++r) {
                    const float x = acc[i][j][r] + bv;
                    ob[rbase + (long)r * NDIM] = (__bf16)(1.0f / (1.0f + __expf(-x)));
                }
            }
        }
    }
}

extern "C" void kernel_launch(void* const* d_in, const int* in_sizes, int n_in,
                              void* d_out, int out_size, void* d_ws,
                              size_t ws_size, hipStream_t stream) {
    const void* X = d_in[0];     // input_data (8192 x 4096)
    const void* W = d_in[1];     // W (4096 x 4096), K x N
    const void* bias = d_in[2];  // hidden_bias (4096)

    const size_t wt_bytes = (size_t)KDIM * NDIM * sizeof(__bf16);  // 33.5 MB
    const size_t xb_bytes = (size_t)MDIM * KDIM * sizeof(__bf16);  // 67 MB
    dim3 gg(NDIM / 128, MDIM / 128);  // 32 x 64

    if (ws_size >= wt_bytes + xb_bytes) {
        __bf16* WT = (__bf16*)d_ws;
        __bf16* Xb = (__bf16*)((char*)d_ws + wt_bytes);
        prep<<<8192 + 4096, 256, 0, stream>>>(X, W, Xb, WT);
        gemm_bias_sigmoid<0><<<gg, 256, 0, stream>>>(X, Xb, W, WT, bias, d_out);
    } else if (ws_size >= wt_bytes) {
        __bf16* WT = (__bf16*)d_ws;
        transpose_w<<<dim3(NDIM / 64, KDIM / 64), 256, 0, stream>>>(X, W, WT);
        gemm_bias_sigmoid<1><<<gg, 256, 0, stream>>>(X, nullptr, W, WT, bias, d_out);
    } else {
        gemm_bias_sigmoid<2><<<gg, 256, 0, stream>>>(X, nullptr, W, nullptr, bias, d_out);
    }
}

// Round 4
// 598.940 us; speedup vs baseline: 1.1034x; 1.1034x over previous
//
#include <hip/hip_runtime.h>
#include <cstdint>

// out = sigmoid(X @ W + b)
// X: (8192 x 4096) fp32 (detected), W: (4096 x 4096) fp32 K x N, b: (4096).
// Pipeline: prep (X->bf16, W->WT bf16 transposed) then bf16 MFMA GEMM,
// BK=64 K-stages with XOR-swizzled LDS (conflict-free b128 reads) and
// fused bias+sigmoid epilogue.
#define MDIM 8192
#define NDIM 4096
#define KDIM 4096

typedef __bf16 bf16x8 __attribute__((ext_vector_type(8)));
typedef float f32x4 __attribute__((ext_vector_type(4)));

__device__ __forceinline__ void gload_lds16(const void* g, void* l) {
    // async global->LDS, 16B/lane; LDS dest = wave-uniform base + lane*16
    __builtin_amdgcn_global_load_lds(
        (const __attribute__((address_space(1))) uint32_t*)g,
        (__attribute__((address_space(3))) uint32_t*)l, 16, 0, 0);
}

__device__ __forceinline__ unsigned short bf16_bits(float f) {
    __bf16 b = (__bf16)f;
    return __builtin_bit_cast(unsigned short, b);
}

// Called by ALL threads (uses __syncthreads_and). 1 if fp32, 0 if bf16.
__device__ __forceinline__ int detect_f32(const void* X) {
    int ok = 1;
    if (threadIdx.x < 128) {
        unsigned short h = ((const unsigned short*)X)[threadIdx.x];
        ok = (h <= 0x3F80);
    }
    return __syncthreads_and(ok) ? 0 : 1;
}

// ---------------- prep: X fp32->bf16 AND W (KxN) -> WT (NxK) bf16 ----------
__global__ __launch_bounds__(256) void prep(const void* __restrict__ X,
                                            const void* __restrict__ W,
                                            __bf16* __restrict__ Xb,
                                            __bf16* __restrict__ WT) {
    const int f32 = detect_f32(X);
    const int t = threadIdx.x;
    if (blockIdx.x < 8192) {
        if (!f32) return;  // bf16 mode: GEMM reads X directly
        const float* Xf = (const float*)X;
        const long base = ((long)blockIdx.x * 256 + t) * 16;
#pragma unroll
        for (int c = 0; c < 2; ++c) {
            float4 v0 = *(const float4*)(Xf + base + c * 8);
            float4 v1 = *(const float4*)(Xf + base + c * 8 + 4);
            unsigned short r[8] = {bf16_bits(v0.x), bf16_bits(v0.y),
                                   bf16_bits(v0.z), bf16_bits(v0.w),
                                   bf16_bits(v1.x), bf16_bits(v1.y),
                                   bf16_bits(v1.z), bf16_bits(v1.w)};
            *(uint4*)(Xb + base + c * 8) = *(const uint4*)r;
        }
        return;
    }
    __shared__ unsigned short tile[64 * 65];
    const int bid = blockIdx.x - 8192;
    const int n0 = (bid & 63) * 64;
    const int k0 = (bid >> 6) * 64;
    if (f32) {
        const float* Wf = (const float*)W;
#pragma unroll
        for (int p = 0; p < 4; ++p) {
            const int ch = p * 256 + t;
            const int kr = ch >> 4;
            const int nc = ch & 15;
            float4 v = *(const float4*)(Wf + (long)(k0 + kr) * NDIM + n0 + nc * 4);
            tile[(nc * 4 + 0) * 65 + kr] = bf16_bits(v.x);
            tile[(nc * 4 + 1) * 65 + kr] = bf16_bits(v.y);
            tile[(nc * 4 + 2) * 65 + kr] = bf16_bits(v.z);
            tile[(nc * 4 + 3) * 65 + kr] = bf16_bits(v.w);
        }
    } else {
        const __bf16* Wb = (const __bf16*)W;
#pragma unroll
        for (int p = 0; p < 2; ++p) {
            const int ch = p * 256 + t;
            const int kr = ch >> 3;
            const int nc = ch & 7;
            uint4 v = *(const uint4*)(Wb + (long)(k0 + kr) * NDIM + n0 + nc * 8);
            const unsigned short* e = (const unsigned short*)&v;
#pragma unroll
            for (int i = 0; i < 8; ++i) tile[(nc * 8 + i) * 65 + kr] = e[i];
        }
    }
    __syncthreads();
#pragma unroll
    for (int p = 0; p < 2; ++p) {
        const int ch = p * 256 + t;
        const int nr = ch >> 3;
        const int kc = ch & 7;
        unsigned short r[8];
#pragma unroll
        for (int i = 0; i < 8; ++i) r[i] = tile[nr * 65 + kc * 8 + i];
        *(uint4*)(WT + (long)(n0 + nr) * KDIM + k0 + kc * 8) = *(uint4*)r;
    }
}

// stand-alone transpose for MODE 1 (no Xb workspace)
__global__ __launch_bounds__(256) void transpose_w(const void* __restrict__ X,
                                                   const void* __restrict__ W,
                                                   __bf16* __restrict__ WT) {
    __shared__ unsigned short tile[64 * 65];
    const int f32 = detect_f32(X);
    const int t = threadIdx.x;
    const int k0 = blockIdx.y * 64;
    const int n0 = blockIdx.x * 64;
    if (f32) {
        const float* Wf = (const float*)W;
#pragma unroll
        for (int p = 0; p < 4; ++p) {
            const int ch = p * 256 + t;
            const int kr = ch >> 4;
            const int nc = ch & 15;
            float4 v = *(const float4*)(Wf + (long)(k0 + kr) * NDIM + n0 + nc * 4);
            tile[(nc * 4 + 0) * 65 + kr] = bf16_bits(v.x);
            tile[(nc * 4 + 1) * 65 + kr] = bf16_bits(v.y);
            tile[(nc * 4 + 2) * 65 + kr] = bf16_bits(v.z);
            tile[(nc * 4 + 3) * 65 + kr] = bf16_bits(v.w);
        }
    } else {
        const __bf16* Wb = (const __bf16*)W;
#pragma unroll
        for (int p = 0; p < 2; ++p) {
            const int ch = p * 256 + t;
            const int kr = ch >> 3;
            const int nc = ch & 7;
            uint4 v = *(const uint4*)(Wb + (long)(k0 + kr) * NDIM + n0 + nc * 8);
            const unsigned short* e = (const unsigned short*)&v;
#pragma unroll
            for (int i = 0; i < 8; ++i) tile[(nc * 8 + i) * 65 + kr] = e[i];
        }
    }
    __syncthreads();
#pragma unroll
    for (int p = 0; p < 2; ++p) {
        const int ch = p * 256 + t;
        const int nr = ch >> 3;
        const int kc = ch & 7;
        unsigned short r[8];
#pragma unroll
        for (int i = 0; i < 8; ++i) r[i] = tile[nr * 65 + kc * 8 + i];
        *(uint4*)(WT + (long)(n0 + nr) * KDIM + k0 + kc * 8) = *(uint4*)r;
    }
}

// ---------------- fused GEMM + bias + sigmoid ----------------
// MODE 0: BK=64, XOR-swizzled LDS, A/B via global_load_lds
//   LDS row = 64 elems = 8 x 16B chunks; chunk slot c8 of row r holds global
//   chunk (c8 ^ (r&7)). Staging stays glds-contiguous (lane = r8*8+c8 fetches
//   global chunk c8^r8); fragment read uses chunk' = (h*4+quad)^(lrow&7),
//   which spreads each quad's 16 lanes across all 8 bank groups (2/group =
//   wave64 floor, free). Unswizzled BK=64 put all 16 lanes of a quad on one
//   bank group (stride 128B = 32 banks): SQ_LDS_BANK_CONFLICT 3.3e7->1.0e8.
// MODE 1/2: round-2-verified BK=32 fallbacks.
template <int MODE>
__global__ __launch_bounds__(256) void gemm_bias_sigmoid(
    const void* __restrict__ X, const __bf16* __restrict__ Xb,
    const void* __restrict__ Wp, const __bf16* __restrict__ WT,
    const void* __restrict__ bias, void* __restrict__ out) {
    __shared__ __bf16 sA[128 * 64];
    __shared__ __bf16 sB[128 * 64];
    const int f32 = detect_f32(X);
    const int t = threadIdx.x;
    const int lane = t & 63;
    const int wid = t >> 6;
    const int m0 = blockIdx.y * 128;
    const int n0 = blockIdx.x * 128;
    const int wm = (wid & 1) * 64;
    const int wn = (wid >> 1) * 64;
    const int lrow = lane & 15;
    const int quad = lane >> 4;

    f32x4 acc[4][4] = {};

    if constexpr (MODE == 0) {
        const __bf16* Abf = f32 ? Xb : (const __bf16*)X;
        const int r8 = lane >> 3;              // row within 8-row slab
        const int c8 = lane & 7;               // LDS chunk slot
        const int cs = (c8 ^ r8) * 8;          // swizzled global chunk offset
        const __bf16* gA = Abf + (long)(m0 + wid * 32 + r8) * KDIM + cs;
        const __bf16* gB = WT + (long)(n0 + wid * 32 + r8) * KDIM + cs;
        __bf16* lA = sA + wid * 32 * 64;       // wave-uniform LDS bases
        __bf16* lB = sB + wid * 32 * 64;
        // per-lane swizzled fragment offsets (hoisted out of K-loop)
        const int l7 = lrow & 7;
        const __bf16* pa0 = sA + (wm + lrow) * 64;
        const __bf16* pb0 = sB + (wn + lrow) * 64;
        const int sw[8] = {(0 ^ l7) * 8, (1 ^ l7) * 8, (2 ^ l7) * 8,
                           (3 ^ l7) * 8, (4 ^ l7) * 8, (5 ^ l7) * 8,
                           (6 ^ l7) * 8, (7 ^ l7) * 8};

        for (int kt = 0; kt < KDIM / 64; ++kt) {
            const int kb = kt * 64;
#pragma unroll
            for (int i = 0; i < 4; ++i) {
                gload_lds16(gA + kb + (long)(i * 8) * KDIM, lA + i * 512);
                gload_lds16(gB + kb + (long)(i * 8) * KDIM, lB + i * 512);
            }
            __syncthreads();
#pragma unroll
            for (int h = 0; h < 2; ++h) {
                bf16x8 aF[4], bF[4];
                const int so = sw[h * 4 + quad];
#pragma unroll
                for (int i = 0; i < 4; ++i)
                    aF[i] = *(const bf16x8*)(pa0 + i * 1024 + so);
#pragma unroll
                for (int j = 0; j < 4; ++j)
                    bF[j] = *(const bf16x8*)(pb0 + j * 1024 + so);
#pragma unroll
                for (int i = 0; i < 4; ++i)
#pragma unroll
                    for (int j = 0; j < 4; ++j)
                        acc[i][j] = __builtin_amdgcn_mfma_f32_16x16x32_bf16(
                            aF[i], bF[j], acc[i][j], 0, 0, 0);
            }
            __syncthreads();
        }
    } else {
        // ---- BK=32 fallback paths ----
        const int srow = t >> 2;
        const int schk = t & 3;
        __bf16* ldsA = sA + wid * 512;
        __bf16* ldsB = sB + wid * 512;
        const int arow = t >> 1;
        const int acol = (t & 1) * 16;
        const int fp = t & 15;
        const int fc = t >> 4;
        uint32_t* sB32 = (uint32_t*)sB;

        auto compute = [&]() {
            bf16x8 aF[4], bF[4];
            const __bf16* pa = sA + (wm + lrow) * 32 + quad * 8;
            const __bf16* pb = sB + (wn + lrow) * 32 + quad * 8;
#pragma unroll
            for (int i = 0; i < 4; ++i) aF[i] = *(const bf16x8*)(pa + i * 512);
#pragma unroll
            for (int j = 0; j < 4; ++j) bF[j] = *(const bf16x8*)(pb + j * 512);
#pragma unroll
            for (int i = 0; i < 4; ++i)
#pragma unroll
                for (int j = 0; j < 4; ++j)
                    acc[i][j] = __builtin_amdgcn_mfma_f32_16x16x32_bf16(
                        aF[i], bF[j], acc[i][j], 0, 0, 0);
        };

        if (MODE == 1 && !f32) {
            const __bf16* gA = (const __bf16*)X + (long)(m0 + srow) * KDIM + schk * 8;
            const __bf16* gB = WT + (long)(n0 + srow) * KDIM + schk * 8;
            for (int kt = 0; kt < KDIM / 32; ++kt) {
                const __bf16* a0 = gA + kt * 32;
                gload_lds16(a0, ldsA);
                gload_lds16(a0 + (long)64 * KDIM, ldsA + 2048);
                const __bf16* b0 = gB + kt * 32;
                gload_lds16(b0, ldsB);
                gload_lds16(b0 + (long)64 * KDIM, ldsB + 2048);
                __syncthreads();
                compute();
                __syncthreads();
            }
        } else if (MODE == 1) {
            const float* Xf = (const float*)X;
            const __bf16* gB = WT + (long)(n0 + srow) * KDIM + schk * 8;
            for (int kt = 0; kt < KDIM / 32; ++kt) {
                const __bf16* b0 = gB + kt * 32;
                gload_lds16(b0, ldsB);
                gload_lds16(b0 + (long)64 * KDIM, ldsB + 2048);
                const float* ap = Xf + (long)(m0 + arow) * KDIM + kt * 32 + acol;
                float4 v0 = *(const float4*)(ap);
                float4 v1 = *(const float4*)(ap + 4);
                float4 v2 = *(const float4*)(ap + 8);
                float4 v3 = *(const float4*)(ap + 12);
                unsigned short r[16] = {
                    bf16_bits(v0.x), bf16_bits(v0.y), bf16_bits(v0.z), bf16_bits(v0.w),
                    bf16_bits(v1.x), bf16_bits(v1.y), bf16_bits(v1.z), bf16_bits(v1.w),
                    bf16_bits(v2.x), bf16_bits(v2.y), bf16_bits(v2.z), bf16_bits(v2.w),
                    bf16_bits(v3.x), bf16_bits(v3.y), bf16_bits(v3.z), bf16_bits(v3.w)};
                *(uint4*)(sA + arow * 32 + acol) = *(const uint4*)(r);
                *(uint4*)(sA + arow * 32 + acol + 8) = *(const uint4*)(r + 8);
                __syncthreads();
                compute();
                __syncthreads();
            }
        } else if (MODE == 2 && !f32) {
            const __bf16* gA = (const __bf16*)X + (long)(m0 + srow) * KDIM + schk * 8;
            const __bf16* Wb = (const __bf16*)Wp;
            for (int kt = 0; kt < KDIM / 32; ++kt) {
                const __bf16* a0 = gA + kt * 32;
                gload_lds16(a0, ldsA);
                gload_lds16(a0 + (long)64 * KDIM, ldsA + 2048);
                const __bf16* w0 = Wb + (long)(kt * 32 + 2 * fp) * NDIM + n0 + fc * 8;
                uint4 g0 = *(const uint4*)(w0);
                uint4 g1 = *(const uint4*)(w0 + NDIM);
                const unsigned short* e0 = (const unsigned short*)&g0;
                const unsigned short* e1 = (const unsigned short*)&g1;
#pragma unroll
                for (int i = 0; i < 8; ++i)
                    sB32[(fc * 8 + i) * 16 + fp] =
                        (uint32_t)e0[i] | ((uint32_t)e1[i] << 16);
                __syncthreads();
                compute();
                __syncthreads();
            }
        } else if (MODE == 2) {
            const float* Xf = (const float*)X;
            const float* Wf = (const float*)Wp;
            for (int kt = 0; kt < KDIM / 32; ++kt) {
                const float* ap = Xf + (long)(m0 + arow) * KDIM + kt * 32 + acol;
                float4 v0 = *(const float4*)(ap);
                float4 v1 = *(const float4*)(ap + 4);
                float4 v2 = *(const float4*)(ap + 8);
                float4 v3 = *(const float4*)(ap + 12);
                unsigned short r[16] = {
                    bf16_bits(v0.x), bf16_bits(v0.y), bf16_bits(v0.z), bf16_bits(v0.w),
                    bf16_bits(v1.x), bf16_bits(v1.y), bf16_bits(v1.z), bf16_bits(v1.w),
                    bf16_bits(v2.x), bf16_bits(v2.y), bf16_bits(v2.z), bf16_bits(v2.w),
                    bf16_bits(v3.x), bf16_bits(v3.y), bf16_bits(v3.z), bf16_bits(v3.w)};
                *(uint4*)(sA + arow * 32 + acol) = *(const uint4*)(r);
                *(uint4*)(sA + arow * 32 + acol + 8) = *(const uint4*)(r + 8);
                const float* w0 = Wf + (long)(kt * 32 + 2 * fp) * NDIM + n0 + fc * 8;
                float4 u0 = *(const float4*)(w0);
                float4 u1 = *(const float4*)(w0 + 4);
                float4 u2 = *(const float4*)(w0 + NDIM);
                float4 u3 = *(const float4*)(w0 + NDIM + 4);
                float k0v[8] = {u0.x, u0.y, u0.z, u0.w, u1.x, u1.y, u1.z, u1.w};
                float k1v[8] = {u2.x, u2.y, u2.z, u2.w, u3.x, u3.y, u3.z, u3.w};
#pragma unroll
                for (int i = 0; i < 8; ++i)
                    sB32[(fc * 8 + i) * 16 + fp] =
                        (uint32_t)bf16_bits(k0v[i]) |
                        ((uint32_t)bf16_bits(k1v[i]) << 16);
                __syncthreads();
                compute();
                __syncthreads();
            }
        }
    }

    // epilogue: C/D layout col=lane&15, row=quad*4+reg
    const int crow = m0 + wm + quad * 4;
    if (f32) {
        float* of = (float*)out;
        const float* bf = (const float*)bias;
#pragma unroll
        for (int j = 0; j < 4; ++j) {
            const int col = n0 + wn + j * 16 + lrow;
            const float bv = bf[col];
#pragma unroll
            for (int i = 0; i < 4; ++i) {
                const long rbase = (long)(crow + i * 16) * NDIM + col;
#pragma unroll
                for (int r = 0; r < 4; ++r) {
                    const float x = acc[i][j][r] + bv;
                    of[rbase + (long)r * NDIM] = 1.0f / (1.0f + __expf(-x));
                }
            }
        }
    } else {
        __bf16* ob = (__bf16*)out;
        const __bf16* bb = (const __bf16*)bias;
#pragma unroll
        for (int j = 0; j < 4; ++j) {
            const int col = n0 + wn + j * 16 + lrow;
            const float bv = (float)bb[col];
#pragma unroll
            for (int i = 0; i < 4; ++i) {
                const long rbase = (long)(crow + i * 16) * NDIM + col;
#pragma unroll
                for (int r = 0; r < 4; ++r) {
                    const float x = acc[i][j][r] + bv;
                    ob[rbase + (long)r * NDIM] = (__bf16)(1.0f / (1.0f + __expf(-x)));
                }
            }
        }
    }
}

extern "C" void kernel_launch(void* const* d_in, const int* in_sizes, int n_in,
                              void* d_out, int out_size, void* d_ws,
                              size_t ws_size, hipStream_t stream) {
    const void* X = d_in[0];     // input_data (8192 x 4096)
    const void* W = d_in[1];     // W (4096 x 4096), K x N
    const void* bias = d_in[2];  // hidden_bias (4096)

    const size_t wt_bytes = (size_t)KDIM * NDIM * sizeof(__bf16);  // 33.5 MB
    const size_t xb_bytes = (size_t)MDIM * KDIM * sizeof(__bf16);  // 67 MB
    dim3 gg(NDIM / 128, MDIM / 128);  // 32 x 64

    if (ws_size >= wt_bytes + xb_bytes) {
        __bf16* WT = (__bf16*)d_ws;
        __bf16* Xb = (__bf16*)((char*)d_ws + wt_bytes);
        prep<<<8192 + 4096, 256, 0, stream>>>(X, W, Xb, WT);
        gemm_bias_sigmoid<0><<<gg, 256, 0, stream>>>(X, Xb, W, WT, bias, d_out);
    } else if (ws_size >= wt_bytes) {
        __bf16* WT = (__bf16*)d_ws;
        transpose_w<<<dim3(NDIM / 64, KDIM / 64), 256, 0, stream>>>(X, W, WT);
        gemm_bias_sigmoid<1><<<gg, 256, 0, stream>>>(X, nullptr, W, WT, bias, d_out);
    } else {
        gemm_bias_sigmoid<2><<<gg, 256, 0, stream>>>(X, nullptr, W, nullptr, bias, d_out);
    }
}